// Round 6
// baseline (63.012 us; speedup 1.0000x reference)
//
#include <hip/hip_runtime.h>
#include <math.h>

#define WAY   32
#define QUERY 128
#define FEAT  640
#define NPAIR 992
#define WQ    4096

typedef short bf16x8  __attribute__((ext_vector_type(8)));
typedef short short4v __attribute__((ext_vector_type(4)));
typedef float f32x4   __attribute__((ext_vector_type(4)));

static __device__ __forceinline__ float leaky(float v) {
    return v >= 0.0f ? v : 0.2f * v;
}
static __device__ __forceinline__ float dot4(float4 a, float4 b) {
    return a.x * b.x + a.y * b.y + a.z * b.z + a.w * b.w;
}
static __device__ __forceinline__ unsigned bf16_rne(float x) {
    unsigned u = __builtin_bit_cast(unsigned, x);
    return (u + 0x7FFFu + ((u >> 16) & 1u)) >> 16;
}
static __device__ __forceinline__ void split2(float x, short& hi, short& lo) {
    unsigned h = bf16_rne(x);
    float fh = __builtin_bit_cast(float, h << 16);
    hi = (short)h;
    lo = (short)bf16_rne(x - fh);
}

// ---------------------------------------------------------------------------
// K_PRE: blocks 0..319:  A'[i,o] = S[i].W1[o,0:640] + b1[o]
//                        B'[i,o] = S[i].W1[o,640:1280]
//        blocks 320..719: split W2 -> whi/wlo bf16
__global__ __launch_bounds__(256) void k_pre(const float* __restrict__ S,
                                             const float* __restrict__ W1,
                                             const float* __restrict__ b1,
                                             const float* __restrict__ W2,
                                             float* __restrict__ A,
                                             float* __restrict__ B,
                                             unsigned short* __restrict__ whi,
                                             unsigned short* __restrict__ wlo) {
    const int bx = blockIdx.x;
    const int tid = threadIdx.x;
    if (bx < 320) {
        __shared__ float4 shS[32][33];
        __shared__ float red1[128];
        const int half = bx / 160;
        const int o0   = (bx % 160) * 4;
        const int i  = tid & 31;
        const int ol = (tid >> 5) & 3;
        const int fh = tid >> 7;
        const float4* Wrow = (const float4*)(W1 + (o0 + ol) * (2 * FEAT) + half * FEAT);
        float acc = 0.0f;
        for (int f0 = 0; f0 < FEAT; f0 += 128) {
            __syncthreads();
#pragma unroll
            for (int s = 0; s < 4; ++s) {
                int flat = tid + 256 * s;
                int si = flat >> 5, sf = flat & 31;
                shS[si][sf] = *(const float4*)(S + si * FEAT + f0 + 4 * sf);
            }
            __syncthreads();
            const int kb = (f0 >> 2) + fh * 16;
#pragma unroll
            for (int k = 0; k < 16; ++k)
                acc += dot4(shS[i][fh * 16 + k], Wrow[kb + k]);
        }
        if (fh) red1[tid & 127] = acc;
        __syncthreads();
        if (!fh) {
            float tot = acc + red1[tid & 127];
            if (half == 0) A[i * FEAT + o0 + ol] = tot + b1[o0 + ol];
            else           B[i * FEAT + o0 + ol] = tot;
        }
    } else {
        int e = (bx - 320) * 1024 + tid * 4;
        float4 w = *(const float4*)(W2 + e);
        short h0, l0, h1, l1, h2, l2, h3, l3;
        split2(w.x, h0, l0); split2(w.y, h1, l1);
        split2(w.z, h2, l2); split2(w.w, h3, l3);
        *(short4v*)(whi + e) = (short4v){h0, h1, h2, h3};
        *(short4v*)(wlo + e) = (short4v){l0, l1, l2, l3};
    }
}

// ---------------------------------------------------------------------------
// K3 v3: h2[p,o] = leaky( h1[p,:] @ W2[o,:] + b2[o] ),  h1 = leaky(A'[i]+B'[j])
// ZERO LDS, zero barriers. Each lane builds its own MFMA A-frag in registers
// (loads A'/B' float4s from L2, add+leaky+split) and reads W2 hi/lo B-frags
// directly from global. 6 independent mfma chains (3 per p-half) pipelined.
// Block 256 thr = 4 waves (wave -> 16-o quarter); tile 32p x 64o; grid 31x10.
__global__ __launch_bounds__(256) void k3_mfma(const float* __restrict__ Ap,
                                               const float* __restrict__ Bp,
                                               const unsigned short* __restrict__ whi,
                                               const unsigned short* __restrict__ wlo,
                                               const float* __restrict__ b2,
                                               float* __restrict__ h2) {
    const int p0 = blockIdx.x * 32;
    const int o0 = blockIdx.y * 64;
    const int tid = threadIdx.x;
    const int w    = tid >> 6;
    const int lane = tid & 63;
    const int l15 = lane & 15, l4 = lane >> 4;

    // per-lane A/B row base pointers for the two p-halves
    const float* Arow0; const float* Brow0;
    const float* Arow1; const float* Brow1;
    {
        int p = p0 + l15;
        int ia = p / 31, jj = p % 31;
        int ja = jj + (jj >= ia ? 1 : 0);
        Arow0 = Ap + ia * FEAT;  Brow0 = Bp + ja * FEAT;
        p = p0 + 16 + l15;
        ia = p / 31; jj = p % 31;
        ja = jj + (jj >= ia ? 1 : 0);
        Arow1 = Ap + ia * FEAT;  Brow1 = Bp + ja * FEAT;
    }
    const unsigned short* Wh = whi + (size_t)(o0 + w * 16 + l15) * FEAT + l4 * 8;
    const unsigned short* Wl = wlo + (size_t)(o0 + w * 16 + l15) * FEAT + l4 * 8;

    f32x4 d0 = {}, d1 = {}, d2 = {}, d3 = {}, d4 = {}, d5 = {};

#pragma unroll 4
    for (int t = 0; t < FEAT / 32; ++t) {
        const int k = t * 32 + l4 * 8;
        // ---- build a-frags in registers (p-half 0 and 1)
        bf16x8 ah0, al0, ah1, al1;
        {
            float4 a0 = *(const float4*)(Arow0 + k);
            float4 a1 = *(const float4*)(Arow0 + k + 4);
            float4 b0 = *(const float4*)(Brow0 + k);
            float4 b1 = *(const float4*)(Brow0 + k + 4);
            float hv[8] = {leaky(a0.x + b0.x), leaky(a0.y + b0.y),
                           leaky(a0.z + b0.z), leaky(a0.w + b0.w),
                           leaky(a1.x + b1.x), leaky(a1.y + b1.y),
                           leaky(a1.z + b1.z), leaky(a1.w + b1.w)};
#pragma unroll
            for (int j = 0; j < 8; ++j) {
                short h, l; split2(hv[j], h, l);
                ah0[j] = h; al0[j] = l;
            }
        }
        {
            float4 a0 = *(const float4*)(Arow1 + k);
            float4 a1 = *(const float4*)(Arow1 + k + 4);
            float4 b0 = *(const float4*)(Brow1 + k);
            float4 b1 = *(const float4*)(Brow1 + k + 4);
            float hv[8] = {leaky(a0.x + b0.x), leaky(a0.y + b0.y),
                           leaky(a0.z + b0.z), leaky(a0.w + b0.w),
                           leaky(a1.x + b1.x), leaky(a1.y + b1.y),
                           leaky(a1.z + b1.z), leaky(a1.w + b1.w)};
#pragma unroll
            for (int j = 0; j < 8; ++j) {
                short h, l; split2(hv[j], h, l);
                ah1[j] = h; al1[j] = l;
            }
        }
        // ---- b-frags straight from global (L2-resident)
        bf16x8 bh = *(const bf16x8*)(Wh + t * 32);
        bf16x8 bl = *(const bf16x8*)(Wl + t * 32);
        // ---- 6 independent chains
        d0 = __builtin_amdgcn_mfma_f32_16x16x32_bf16(ah0, bh, d0, 0, 0, 0);
        d1 = __builtin_amdgcn_mfma_f32_16x16x32_bf16(al0, bh, d1, 0, 0, 0);
        d2 = __builtin_amdgcn_mfma_f32_16x16x32_bf16(ah0, bl, d2, 0, 0, 0);
        d3 = __builtin_amdgcn_mfma_f32_16x16x32_bf16(ah1, bh, d3, 0, 0, 0);
        d4 = __builtin_amdgcn_mfma_f32_16x16x32_bf16(al1, bh, d4, 0, 0, 0);
        d5 = __builtin_amdgcn_mfma_f32_16x16x32_bf16(ah1, bl, d5, 0, 0, 0);
    }

    f32x4 acc0 = d0 + d1 + d2;
    f32x4 acc1 = d3 + d4 + d5;
    const int oo = o0 + w * 16 + l15;
    const float b2v = b2[oo];
#pragma unroll
    for (int r = 0; r < 4; ++r) {
        int pp = p0 + l4 * 4 + r;
        h2[pp * FEAT + oo] = leaky(acc0[r] + b2v);
        pp += 16;
        h2[pp * FEAT + oo] = leaky(acc1[r] + b2v);
    }
}

// ---------------------------------------------------------------------------
// K4: grid (32 wi x 10 f-chunks), 64 thr. c1 = mean_jj h2; m = c1^4;
//     V = -2*m*S, M = m as bf16 hi/lo; palpha[wi*10+ch] = sum_chunk m*S^2.
__global__ __launch_bounds__(64) void k4_ctx(const float* __restrict__ h2,
                                             const float* __restrict__ S,
                                             unsigned short* __restrict__ Vhi,
                                             unsigned short* __restrict__ Vlo,
                                             unsigned short* __restrict__ Mhi,
                                             unsigned short* __restrict__ Mlo,
                                             float* __restrict__ palpha) {
    const int wi = blockIdx.x;
    const int ch = blockIdx.y;
    const int o  = ch * 64 + threadIdx.x;
    float s = 0.0f;
#pragma unroll 31
    for (int jj = 0; jj < 31; ++jj)
        s += h2[(wi * 31 + jj) * FEAT + o];
    float c1 = s * (1.0f / 31.0f);
    float c2 = c1 * c1;
    float m  = c2 * c2;
    float sv = S[wi * FEAT + o];
    short h, l;
    split2(-2.0f * m * sv, h, l);
    Vhi[wi * FEAT + o] = (unsigned short)h;
    Vlo[wi * FEAT + o] = (unsigned short)l;
    split2(m, h, l);
    Mhi[wi * FEAT + o] = (unsigned short)h;
    Mlo[wi * FEAT + o] = (unsigned short)l;

    float part = m * sv * sv;
#pragma unroll
    for (int off = 32; off > 0; off >>= 1)
        part += __shfl_down(part, off, 64);
    if (threadIdx.x == 0) palpha[wi * 10 + ch] = part;
}

// ---------------------------------------------------------------------------
// K5 v2: out[q,wi] = -sqrt( alpha[wi] + sum_f V[wi,f]*Q[q,f] + M[wi,f]*Q[q,f]^2 )
// Grid 256(q-tile) x 2(wi-half) = 512 blocks; 4 waves K-split (160 f each).
// 5 independent mfma chains per wave; deterministic LDS combine.
__global__ __launch_bounds__(256) void k5_mfma(const float* __restrict__ Q,
                                               const unsigned short* __restrict__ Vhi,
                                               const unsigned short* __restrict__ Vlo,
                                               const unsigned short* __restrict__ Mhi,
                                               const unsigned short* __restrict__ Mlo,
                                               const float* __restrict__ palpha,
                                               float* __restrict__ out) {
    __shared__ float red[4][16][16];
    __shared__ float shAl[16];
    const int q0 = blockIdx.x * 16;
    const int by = blockIdx.y;          // wi-half
    const int tid = threadIdx.x;
    const int w    = tid >> 6;
    const int lane = tid & 63;
    const int l15 = lane & 15, l4 = lane >> 4;
    const float* Qrow = Q + (size_t)(q0 + l15) * FEAT + l4 * 8;
    const int wi = by * 16 + l15;
    const unsigned short* vh = Vhi + (size_t)wi * FEAT + l4 * 8;
    const unsigned short* vl = Vlo + (size_t)wi * FEAT + l4 * 8;
    const unsigned short* mh = Mhi + (size_t)wi * FEAT + l4 * 8;
    const unsigned short* ml = Mlo + (size_t)wi * FEAT + l4 * 8;

    f32x4 c0 = {}, c1 = {}, c2 = {}, c3 = {}, c4 = {};

#pragma unroll
    for (int s = 0; s < 5; ++s) {
        const int k0 = w * 160 + s * 32;
        float4 qa = *(const float4*)(Qrow + k0);
        float4 qb = *(const float4*)(Qrow + k0 + 4);
        float qs[8] = {qa.x, qa.y, qa.z, qa.w, qb.x, qb.y, qb.z, qb.w};
        bf16x8 qh, ql, q2h;
#pragma unroll
        for (int j = 0; j < 8; ++j) {
            short h, l;
            split2(qs[j], h, l);
            qh[j] = h; ql[j] = l;
            q2h[j] = (short)bf16_rne(qs[j] * qs[j]);
        }
        bf16x8 fvh = *(const bf16x8*)(vh + k0);
        bf16x8 fvl = *(const bf16x8*)(vl + k0);
        bf16x8 fmh = *(const bf16x8*)(mh + k0);
        bf16x8 fml = *(const bf16x8*)(ml + k0);
        c0 = __builtin_amdgcn_mfma_f32_16x16x32_bf16(qh,  fvh, c0, 0, 0, 0);
        c1 = __builtin_amdgcn_mfma_f32_16x16x32_bf16(ql,  fvh, c1, 0, 0, 0);
        c2 = __builtin_amdgcn_mfma_f32_16x16x32_bf16(qh,  fvl, c2, 0, 0, 0);
        c3 = __builtin_amdgcn_mfma_f32_16x16x32_bf16(q2h, fmh, c3, 0, 0, 0);
        c4 = __builtin_amdgcn_mfma_f32_16x16x32_bf16(q2h, fml, c4, 0, 0, 0);
    }

    f32x4 acc = c0 + c1 + c2 + c3 + c4;
#pragma unroll
    for (int r = 0; r < 4; ++r)
        red[w][l4 * 4 + r][l15] = acc[r];
    if (tid < 16) {
        float a = 0.0f;
#pragma unroll
        for (int c = 0; c < 10; ++c)
            a += palpha[(by * 16 + tid) * 10 + c];
        shAl[tid] = a;
    }
    __syncthreads();

    {
        const int qs_ = tid >> 4, wl = tid & 15;
        float v = red[0][qs_][wl] + red[1][qs_][wl] + red[2][qs_][wl] + red[3][qs_][wl];
        float d2 = shAl[wl] + v;
        out[(q0 + qs_) * WAY + by * 16 + wl] = -sqrtf(fmaxf(d2, 0.0f));
    }
}

extern "C" void kernel_launch(void* const* d_in, const int* in_sizes, int n_in,
                              void* d_out, int out_size, void* d_ws, size_t ws_size,
                              hipStream_t stream) {
    const float* S  = (const float*)d_in[0];   // [32, 640]
    const float* Q  = (const float*)d_in[1];   // [4096, 640]
    const float* W1 = (const float*)d_in[2];   // [640, 1280]
    const float* b1 = (const float*)d_in[3];   // [640]
    const float* W2 = (const float*)d_in[4];   // [640, 640]
    const float* b2 = (const float*)d_in[5];   // [640]
    float* out = (float*)d_out;                // [4096, 32]

    char* wsb = (char*)d_ws;
    float* A      = (float*)wsb;                               // 32*640 f32
    float* B      = A + WAY * FEAT;                            // 32*640 f32
    float* h2     = B + WAY * FEAT;                            // 992*640 f32
    float* palpha = h2 + NPAIR * FEAT;                         // 320 f32
    unsigned short* whi = (unsigned short*)(palpha + 320);     // 640*640 u16
    unsigned short* wlo = whi + FEAT * FEAT;                   // 640*640 u16
    unsigned short* Vhi = wlo + FEAT * FEAT;                   // 32*640 u16
    unsigned short* Vlo = Vhi + WAY * FEAT;
    unsigned short* Mhi = Vlo + WAY * FEAT;
    unsigned short* Mlo = Mhi + WAY * FEAT;
    (void)ws_size; (void)in_sizes; (void)n_in; (void)out_size;

    k_pre<<<dim3(720), dim3(256), 0, stream>>>(S, W1, b1, W2, A, B, whi, wlo);
    k3_mfma<<<dim3(31, 10), dim3(256), 0, stream>>>(A, B, whi, wlo, b2, h2);
    k4_ctx<<<dim3(WAY, 10), dim3(64), 0, stream>>>(h2, S, Vhi, Vlo, Mhi, Mlo, palpha);
    k5_mfma<<<dim3(WQ / 16, 2), dim3(256), 0, stream>>>(Q, Vhi, Vlo, Mhi, Mlo, palpha, out);
}

// Round 7
// 46.581 us; speedup vs baseline: 1.3527x; 1.3527x over previous
//
#include <hip/hip_runtime.h>
#include <math.h>

#define WAY   32
#define QUERY 128
#define FEAT  640
#define NPAIR 992
#define WQ    4096

typedef short bf16x8  __attribute__((ext_vector_type(8)));
typedef short short4v __attribute__((ext_vector_type(4)));
typedef float f32x4   __attribute__((ext_vector_type(4)));

static __device__ __forceinline__ float leaky(float v) {
    return v >= 0.0f ? v : 0.2f * v;
}
static __device__ __forceinline__ float dot4(float4 a, float4 b) {
    return a.x * b.x + a.y * b.y + a.z * b.z + a.w * b.w;
}
static __device__ __forceinline__ unsigned bf16_rne(float x) {
    unsigned u = __builtin_bit_cast(unsigned, x);
    return (u + 0x7FFFu + ((u >> 16) & 1u)) >> 16;
}
static __device__ __forceinline__ void split2(float x, short& hi, short& lo) {
    unsigned h = bf16_rne(x);
    float fh = __builtin_bit_cast(float, h << 16);
    hi = (short)h;
    lo = (short)bf16_rne(x - fh);
}

// ---------------------------------------------------------------------------
// K_PRE: blocks 0..319:  A'[i,o] = S[i].W1[o,0:640] + b1[o]
//                        B'[i,o] = S[i].W1[o,640:1280]
//        blocks 320..719: split W2 -> whi/wlo bf16
__global__ __launch_bounds__(256) void k_pre(const float* __restrict__ S,
                                             const float* __restrict__ W1,
                                             const float* __restrict__ b1,
                                             const float* __restrict__ W2,
                                             float* __restrict__ A,
                                             float* __restrict__ B,
                                             unsigned short* __restrict__ whi,
                                             unsigned short* __restrict__ wlo) {
    const int bx = blockIdx.x;
    const int tid = threadIdx.x;
    if (bx < 320) {
        __shared__ float4 shS[32][33];
        __shared__ float red1[128];
        const int half = bx / 160;
        const int o0   = (bx % 160) * 4;
        const int i  = tid & 31;
        const int ol = (tid >> 5) & 3;
        const int fh = tid >> 7;
        const float4* Wrow = (const float4*)(W1 + (o0 + ol) * (2 * FEAT) + half * FEAT);
        float acc = 0.0f;
        for (int f0 = 0; f0 < FEAT; f0 += 128) {
            __syncthreads();
#pragma unroll
            for (int s = 0; s < 4; ++s) {
                int flat = tid + 256 * s;
                int si = flat >> 5, sf = flat & 31;
                shS[si][sf] = *(const float4*)(S + si * FEAT + f0 + 4 * sf);
            }
            __syncthreads();
            const int kb = (f0 >> 2) + fh * 16;
#pragma unroll
            for (int k = 0; k < 16; ++k)
                acc += dot4(shS[i][fh * 16 + k], Wrow[kb + k]);
        }
        if (fh) red1[tid & 127] = acc;
        __syncthreads();
        if (!fh) {
            float tot = acc + red1[tid & 127];
            if (half == 0) A[i * FEAT + o0 + ol] = tot + b1[o0 + ol];
            else           B[i * FEAT + o0 + ol] = tot;
        }
    } else {
        int e = (bx - 320) * 1024 + tid * 4;
        float4 w = *(const float4*)(W2 + e);
        short h0, l0, h1, l1, h2, l2, h3, l3;
        split2(w.x, h0, l0); split2(w.y, h1, l1);
        split2(w.z, h2, l2); split2(w.w, h3, l3);
        *(short4v*)(whi + e) = (short4v){h0, h1, h2, h3};
        *(short4v*)(wlo + e) = (short4v){l0, l1, l2, l3};
    }
}

// ---------------------------------------------------------------------------
// K3 (R4 known-good main loop + colsum epilogue):
// GEMM h2 = leaky(h1 @ W2^T + b2) computed in MFMA accs, but h2 is NEVER
// stored: the block directly column-sums its 32 p-rows (split at the wi
// boundary) into part[ptile][2][640]. bf16x3 MFMA 16x16x32, 4 waves, tile
// 32p x 64o, double-buffered LDS, one barrier per K-step.
__global__ __launch_bounds__(256) void k3_mfma(const float* __restrict__ Ap,
                                               const float* __restrict__ Bp,
                                               const unsigned short* __restrict__ whi,
                                               const unsigned short* __restrict__ wlo,
                                               const float* __restrict__ b2,
                                               float* __restrict__ part) {
    __shared__ __align__(16) short lsA[2][2][4][32][8];  // [buf][hi/lo][kc][prow][8]
    __shared__ __align__(16) short lsB[2][2][4][64][8];  // [buf][hi/lo][kc][orow][8]
    const int pt = blockIdx.x;
    const int p0 = pt * 32;
    const int o0 = blockIdx.y * 64;
    const int tid = threadIdx.x;
    const int w    = tid >> 6;
    const int lane = tid & 63;
    const int l15 = lane & 15, l4 = lane >> 4;

    // A-staging coords: 32 rows x 32 k, one float4 per thread
    const int ar  = tid >> 3;
    const int ac4 = (tid & 7) << 2;
    const int akc = ac4 >> 3;
    const int aof = ac4 & 7;
    const int p = p0 + ar;
    const int ia = p / 31;
    const int jj = p % 31;
    const int ja = jj + (jj >= ia ? 1 : 0);
    const float* Arow = Ap + ia * FEAT;   // b1 folded in
    const float* Brow = Bp + ja * FEAT;
    // B-staging coords: 64 rows x 32 k, one bf16x8 per thread per array
    const int br = tid >> 2;
    const int bk = tid & 3;
    const unsigned short* Whr = whi + (size_t)(o0 + br) * FEAT;
    const unsigned short* Wlr = wlo + (size_t)(o0 + br) * FEAT;

    float4 ra, rb;
    bf16x8 rwh, rwl;
    ra  = *(const float4*)(Arow + ac4);
    rb  = *(const float4*)(Brow + ac4);
    rwh = *(const bf16x8*)(Whr + bk * 8);
    rwl = *(const bf16x8*)(Wlr + bk * 8);

    f32x4 acc[2] = {};

    for (int t = 0; t < FEAT / 32; ++t) {
        const int buf = t & 1;
        {
            float h[4];
            h[0] = leaky(ra.x + rb.x);
            h[1] = leaky(ra.y + rb.y);
            h[2] = leaky(ra.z + rb.z);
            h[3] = leaky(ra.w + rb.w);
            short hi[4], lo[4];
#pragma unroll
            for (int j = 0; j < 4; ++j) split2(h[j], hi[j], lo[j]);
            *(short4v*)&lsA[buf][0][akc][ar][aof] = (short4v){hi[0], hi[1], hi[2], hi[3]};
            *(short4v*)&lsA[buf][1][akc][ar][aof] = (short4v){lo[0], lo[1], lo[2], lo[3]};
            *(bf16x8*)&lsB[buf][0][bk][br][0] = rwh;
            *(bf16x8*)&lsB[buf][1][bk][br][0] = rwl;
        }
        __syncthreads();
        if (t < FEAT / 32 - 1) {
            const int f0 = (t + 1) * 32;
            ra  = *(const float4*)(Arow + f0 + ac4);
            rb  = *(const float4*)(Brow + f0 + ac4);
            rwh = *(const bf16x8*)(Whr + f0 + bk * 8);
            rwl = *(const bf16x8*)(Wlr + f0 + bk * 8);
        }
        bf16x8 ah[2], al[2], bh, bl;
#pragma unroll
        for (int rt = 0; rt < 2; ++rt) {
            ah[rt] = *(const bf16x8*)&lsA[buf][0][l4][rt * 16 + l15][0];
            al[rt] = *(const bf16x8*)&lsA[buf][1][l4][rt * 16 + l15][0];
        }
        bh = *(const bf16x8*)&lsB[buf][0][l4][w * 16 + l15][0];
        bl = *(const bf16x8*)&lsB[buf][1][l4][w * 16 + l15][0];
#pragma unroll
        for (int rt = 0; rt < 2; ++rt) {
            acc[rt] = __builtin_amdgcn_mfma_f32_16x16x32_bf16(ah[rt], bh, acc[rt], 0, 0, 0);
            acc[rt] = __builtin_amdgcn_mfma_f32_16x16x32_bf16(ah[rt], bl, acc[rt], 0, 0, 0);
            acc[rt] = __builtin_amdgcn_mfma_f32_16x16x32_bf16(al[rt], bh, acc[rt], 0, 0, 0);
        }
    }

    // ---- colsum epilogue: rows < rsplit -> wi0 (h=0), else wi0+1 (h=1)
    const int oo = o0 + w * 16 + l15;
    const float b2v = b2[oo];
    const int wi0 = p0 / 31;
    const int rsplit = (wi0 + 1) * 31 - p0;
    float s0 = 0.0f, s1 = 0.0f;
#pragma unroll
    for (int r = 0; r < 4; ++r) {
        float v = leaky(acc[0][r] + b2v);           // row l4*4+r
        if (l4 * 4 + r < rsplit) s0 += v; else s1 += v;
        v = leaky(acc[1][r] + b2v);                  // row 16+l4*4+r
        if (16 + l4 * 4 + r < rsplit) s0 += v; else s1 += v;
    }
    s0 += __shfl_xor(s0, 16, 64);
    s0 += __shfl_xor(s0, 32, 64);
    s1 += __shfl_xor(s1, 16, 64);
    s1 += __shfl_xor(s1, 32, 64);
    if (l4 == 0) {
        part[(pt * 2 + 0) * FEAT + oo] = s0;
        part[(pt * 2 + 1) * FEAT + oo] = s1;
    }
}

// ---------------------------------------------------------------------------
// K5: out[q,wi] = -sqrt( sum_f m*(q-s)^2 ),  m = (colsum/31)^4, expanded as
//   q.(-2 m s) + q^2.m + 1.(m s^2)   -- three MFMA B-operands built IN-REG
// from part[] + S. Grid 256(q-tile) x 2(wi-half); 4 waves K-split (160 f).
// 7 independent mfma chains; alpha folded in via the ones-A-frag term.
__global__ __launch_bounds__(256) void k5_mfma(const float* __restrict__ Q,
                                               const float* __restrict__ part,
                                               const float* __restrict__ S,
                                               float* __restrict__ out) {
    __shared__ float red[4][16][16];
    const int q0 = blockIdx.x * 16;
    const int by = blockIdx.y;
    const int tid = threadIdx.x;
    const int w    = tid >> 6;
    const int lane = tid & 63;
    const int l15 = lane & 15, l4 = lane >> 4;

    const float* Qrow = Q + (size_t)(q0 + l15) * FEAT + l4 * 8;
    const int wi = by * 16 + l15;
    // colsum sources for wi: part rows (pa,ha) and, if pa!=pb, (pb,hb)
    const int pa = (31 * wi) >> 5;
    const int pb = (31 * wi + 30) >> 5;
    const int ha = wi - (32 * pa) / 31;
    const int hb = wi - (32 * pb) / 31;
    const float du = (pa != pb) ? 1.0f : 0.0f;
    const float* pAr = part + (size_t)(pa * 2 + ha) * FEAT + l4 * 8;
    const float* pBr = part + (size_t)(pb * 2 + hb) * FEAT + l4 * 8;
    const float* Srow = S + (size_t)wi * FEAT + l4 * 8;

    bf16x8 ones;
#pragma unroll
    for (int j = 0; j < 8; ++j) ones[j] = (short)0x3F80;

    f32x4 c0 = {}, c1 = {}, c2 = {}, c3 = {}, c4 = {}, c5 = {}, c6 = {};

    for (int s = 0; s < 5; ++s) {
        const int k0 = w * 160 + s * 32;
        // --- Q frags
        float4 qa = *(const float4*)(Qrow + k0);
        float4 qb = *(const float4*)(Qrow + k0 + 4);
        float qs[8] = {qa.x, qa.y, qa.z, qa.w, qb.x, qb.y, qb.z, qb.w};
        bf16x8 qh, ql, q2h;
#pragma unroll
        for (int j = 0; j < 8; ++j) {
            short h, l;
            split2(qs[j], h, l);
            qh[j] = h; ql[j] = l;
            q2h[j] = (short)bf16_rne(qs[j] * qs[j]);
        }
        // --- build V/M/G frags from colsum + S
        float4 ca0 = *(const float4*)(pAr + k0);
        float4 ca1 = *(const float4*)(pAr + k0 + 4);
        float4 cb0 = *(const float4*)(pBr + k0);
        float4 cb1 = *(const float4*)(pBr + k0 + 4);
        float4 sv0 = *(const float4*)(Srow + k0);
        float4 sv1 = *(const float4*)(Srow + k0 + 4);
        float cs[8]  = {ca0.x + du * cb0.x, ca0.y + du * cb0.y,
                        ca0.z + du * cb0.z, ca0.w + du * cb0.w,
                        ca1.x + du * cb1.x, ca1.y + du * cb1.y,
                        ca1.z + du * cb1.z, ca1.w + du * cb1.w};
        float svv[8] = {sv0.x, sv0.y, sv0.z, sv0.w, sv1.x, sv1.y, sv1.z, sv1.w};
        bf16x8 vh, vl, mh, ml, gh, gl;
#pragma unroll
        for (int j = 0; j < 8; ++j) {
            float c1f = cs[j] * (1.0f / 31.0f);
            float c2f = c1f * c1f;
            float m   = c2f * c2f;
            float sv  = svv[j];
            short h, l;
            split2(-2.0f * m * sv, h, l); vh[j] = h; vl[j] = l;
            split2(m, h, l);              mh[j] = h; ml[j] = l;
            split2(m * sv * sv, h, l);    gh[j] = h; gl[j] = l;
        }
        // --- 7 independent chains
        c0 = __builtin_amdgcn_mfma_f32_16x16x32_bf16(qh,   vh, c0, 0, 0, 0);
        c1 = __builtin_amdgcn_mfma_f32_16x16x32_bf16(ql,   vh, c1, 0, 0, 0);
        c2 = __builtin_amdgcn_mfma_f32_16x16x32_bf16(qh,   vl, c2, 0, 0, 0);
        c3 = __builtin_amdgcn_mfma_f32_16x16x32_bf16(q2h,  mh, c3, 0, 0, 0);
        c4 = __builtin_amdgcn_mfma_f32_16x16x32_bf16(q2h,  ml, c4, 0, 0, 0);
        c5 = __builtin_amdgcn_mfma_f32_16x16x32_bf16(ones, gh, c5, 0, 0, 0);
        c6 = __builtin_amdgcn_mfma_f32_16x16x32_bf16(ones, gl, c6, 0, 0, 0);
    }

    f32x4 acc = ((c0 + c1) + (c2 + c3)) + ((c4 + c5) + c6);
#pragma unroll
    for (int r = 0; r < 4; ++r)
        red[w][l4 * 4 + r][l15] = acc[r];
    __syncthreads();

    {
        const int qs_ = tid >> 4, wl = tid & 15;
        float v = red[0][qs_][wl] + red[1][qs_][wl] + red[2][qs_][wl] + red[3][qs_][wl];
        out[(q0 + qs_) * WAY + by * 16 + wl] = -sqrtf(fmaxf(v, 0.0f));
    }
}

extern "C" void kernel_launch(void* const* d_in, const int* in_sizes, int n_in,
                              void* d_out, int out_size, void* d_ws, size_t ws_size,
                              hipStream_t stream) {
    const float* S  = (const float*)d_in[0];   // [32, 640]
    const float* Q  = (const float*)d_in[1];   // [4096, 640]
    const float* W1 = (const float*)d_in[2];   // [640, 1280]
    const float* b1 = (const float*)d_in[3];   // [640]
    const float* W2 = (const float*)d_in[4];   // [640, 640]
    const float* b2 = (const float*)d_in[5];   // [640]
    float* out = (float*)d_out;                // [4096, 32]

    char* wsb = (char*)d_ws;
    float* A    = (float*)wsb;                               // 32*640 f32
    float* B    = A + WAY * FEAT;                            // 32*640 f32
    float* part = B + WAY * FEAT;                            // 31*2*640 f32
    unsigned short* whi = (unsigned short*)(part + 31 * 2 * FEAT);  // 640*640 u16
    unsigned short* wlo = whi + FEAT * FEAT;                 // 640*640 u16
    (void)ws_size; (void)in_sizes; (void)n_in; (void)out_size;

    k_pre<<<dim3(720), dim3(256), 0, stream>>>(S, W1, b1, W2, A, B, whi, wlo);
    k3_mfma<<<dim3(31, 10), dim3(256), 0, stream>>>(A, B, whi, wlo, b2, part);
    k5_mfma<<<dim3(WQ / 16, 2), dim3(256), 0, stream>>>(Q, part, S, out);
}